// Round 10
// baseline (19.138 us; speedup 1.0000x reference)
//
#include <hip/hip_runtime.h>

// CoupledFourierSystem: out[t][j] = b[j] + sum_d W[j][d] * sum_{h,c} A[d][h][c]*cos(w[d][h][c]*s_t + phi[d][h][c])
// S=32768, DIM=64, H=16 (HC=32)
//
// Round 7: round-6 structure (packed phase math, swizzled wave-private LDS
// slab, 8x mfma_f32_16x16x32_f16 matvec) + HYBRID cos: per (k,lane), 20
// cosines on the trans pipe (v_cos_f32) and 12 on the VALU as a degree-14
// even minimax/Taylor poly of cos(2*pi*v), v = fract(x)-0.5 (sign folded into
// pre-negated amplitudes). Balances the trans pipe (diagnosed critical) vs
// the half-idle VALU.

typedef float    f32x2 __attribute__((ext_vector_type(2)));
typedef float    f32x4 __attribute__((ext_vector_type(4)));
typedef _Float16 f16x8 __attribute__((ext_vector_type(8)));

constexpr int S_PTS  = 32768;
constexpr int DIM    = 64;
constexpr int HC     = 32;   // H*2
constexpr int TPW    = 16;   // time points per wave (MFMA M)
constexpr int NTRANS = 10;   // f32x2 pairs evaluated via v_cos (20 cos); rest poly (12 cos)
constexpr float INV_2PI = 0.15915494309189535f;

// cos(2*pi*v) = sum c_k (v^2)^k, |v| <= 0.5 (Taylor in (2*pi*v)^2; trunc err ~8e-6)
__constant__ const float PC0 =  1.0f;
__constant__ const float PC1 = -19.739208802178716f;
__constant__ const float PC2 =  64.93939402266829f;
__constant__ const float PC3 = -85.45681720669371f;
__constant__ const float PC4 =  60.24464137187666f;
__constant__ const float PC5 = -26.42625678337438f;
__constant__ const float PC6 =  7.903536371318467f;
__constant__ const float PC7 = -0.6765966332859438f;

static __device__ __forceinline__ unsigned pkrtz(float x, float y) {
    return __builtin_bit_cast(unsigned, __builtin_amdgcn_cvt_pkrtz(x, y));
}
static __device__ __forceinline__ f16x8 pack8(float4 a, float4 b) {
    union { unsigned u[4]; f16x8 v; } t;
    t.u[0] = pkrtz(a.x, a.y);
    t.u[1] = pkrtz(a.z, a.w);
    t.u[2] = pkrtz(b.x, b.y);
    t.u[3] = pkrtz(b.z, b.w);
    return t.v;
}

__global__ __launch_bounds__(256, 2)
void fourier_fused(const float* __restrict__ s,
                   const float* __restrict__ A,
                   const float* __restrict__ phi,
                   const float* __restrict__ w,
                   const float* __restrict__ Wm,
                   const float* __restrict__ b,
                   float* __restrict__ out)
{
    __shared__ float slab[4][TPW * DIM];   // 4 KB per wave, wave-private

    const int lane = threadIdx.x & 63;
    const int wid  = threadIdx.x >> 6;
    const int t0   = (blockIdx.x * 4 + wid) * TPW;
    const int t16  = lane & 15;
    const int hi   = lane >> 4;

    // ---- Fourier params (lane = d), scaled to revolutions, packed f32x2 ----
    // Amplitudes for poly pairs (i >= NTRANS) pre-negated: poly yields -cos.
    f32x2 a2[16], w2[16], p2[16];
    {
        const float4* A4 = reinterpret_cast<const float4*>(A   + lane * HC);
        const float4* P4 = reinterpret_cast<const float4*>(phi + lane * HC);
        const float4* W4 = reinterpret_cast<const float4*>(w   + lane * HC);
        #pragma unroll
        for (int q = 0; q < 8; ++q) {
            float4 av = A4[q], pv = P4[q], wv = W4[q];
            a2[2*q+0] = f32x2{av.x, av.y};           a2[2*q+1] = f32x2{av.z, av.w};
            p2[2*q+0] = f32x2{pv.x, pv.y} * INV_2PI; p2[2*q+1] = f32x2{pv.z, pv.w} * INV_2PI;
            w2[2*q+0] = f32x2{wv.x, wv.y} * INV_2PI; w2[2*q+1] = f32x2{wv.z, wv.w} * INV_2PI;
        }
        #pragma unroll
        for (int i = NTRANS; i < 16; ++i) a2[i] = -a2[i];
    }

    // ---- B-operand fragments: wf[n][ks] holds W[n*16+t16][ks*32+hi*8 .. +7] ----
    f16x8 wf[4][2];
    float bj[4];
    #pragma unroll
    for (int n = 0; n < 4; ++n) {
        const float* wr = Wm + (n * 16 + t16) * DIM;
        #pragma unroll
        for (int ks = 0; ks < 2; ++ks) {
            float4 v0 = *reinterpret_cast<const float4*>(wr + ks * 32 + hi * 8);
            float4 v1 = *reinterpret_cast<const float4*>(wr + ks * 32 + hi * 8 + 4);
            wf[n][ks] = pack8(v0, v1);
        }
        bj[n] = b[n * 16 + t16];
    }

    // lanes 0..15 hold the wave's 16 time values
    const float sv = s[t0 + t16];
    float* myslab = slab[wid];

    // ---- phase A: 16 Fourier sums -> swizzled LDS slab ----
    #pragma unroll
    for (int k = 0; k < TPW; ++k) {
        const float st = __uint_as_float(__builtin_amdgcn_readlane(__float_as_uint(sv), k));
        const f32x2 st2 = {st, st};
        f32x2 ac0 = {0.f, 0.f}, ac1 = {0.f, 0.f};

        // trans-pipe half: v_cos_f32
        #pragma unroll
        for (int i = 0; i < NTRANS; i += 2) {
            f32x2 ph0 = w2[i+0] * st2 + p2[i+0];   // v_pk_fma_f32
            f32x2 ph1 = w2[i+1] * st2 + p2[i+1];
            f32x2 c0 = { __builtin_amdgcn_cosf(ph0[0]), __builtin_amdgcn_cosf(ph0[1]) };
            f32x2 c1 = { __builtin_amdgcn_cosf(ph1[0]), __builtin_amdgcn_cosf(ph1[1]) };
            ac0 = a2[i+0] * c0 + ac0;
            ac1 = a2[i+1] * c1 + ac1;
        }

        // VALU half: packed even polynomial; a2 pre-negated for these pairs
        #pragma unroll
        for (int i = NTRANS; i < 16; ++i) {
            f32x2 ph = w2[i] * st2 + p2[i];
            f32x2 u  = { __builtin_amdgcn_fractf(ph[0]), __builtin_amdgcn_fractf(ph[1]) };
            f32x2 v  = u - 0.5f;                    // v in [-0.5, 0.5)
            f32x2 r  = v * v;
            f32x2 p  = f32x2{PC7, PC7};
            p = p * r + f32x2{PC6, PC6};
            p = p * r + f32x2{PC5, PC5};
            p = p * r + f32x2{PC4, PC4};
            p = p * r + f32x2{PC3, PC3};
            p = p * r + f32x2{PC2, PC2};
            p = p * r + f32x2{PC1, PC1};
            p = p * r + f32x2{PC0, PC0};            // p = cos(2*pi*v) = -cos(2*pi*x)
            if (i & 1) ac1 = a2[i] * p + ac1;
            else       ac0 = a2[i] * p + ac0;
        }

        const f32x2 acs = ac0 + ac1;
        myslab[(k * 64 + lane) ^ ((k & 7) << 2)] = acs[0] + acs[1];
    }
    asm volatile("s_waitcnt lgkmcnt(0)" ::: "memory");

    // ---- phase C: A-fragments from swizzled slab, 8 MFMAs ----
    f16x8 pa[2];
    #pragma unroll
    for (int ks = 0; ks < 2; ++ks) {
        const int base = t16 * 64 + ks * 32 + hi * 8;
        const int w0 = base       ^ ((t16 & 7) << 2);
        const int w1 = (base + 4) ^ ((t16 & 7) << 2);
        float4 q0 = *reinterpret_cast<const float4*>(myslab + w0);
        float4 q1 = *reinterpret_cast<const float4*>(myslab + w1);
        pa[ks] = pack8(q0, q1);
    }

    f32x4 acc0 = {}, acc1 = {}, acc2 = {}, acc3 = {};
    acc0 = __builtin_amdgcn_mfma_f32_16x16x32_f16(pa[0], wf[0][0], acc0, 0, 0, 0);
    acc0 = __builtin_amdgcn_mfma_f32_16x16x32_f16(pa[1], wf[0][1], acc0, 0, 0, 0);
    acc1 = __builtin_amdgcn_mfma_f32_16x16x32_f16(pa[0], wf[1][0], acc1, 0, 0, 0);
    acc1 = __builtin_amdgcn_mfma_f32_16x16x32_f16(pa[1], wf[1][1], acc1, 0, 0, 0);
    acc2 = __builtin_amdgcn_mfma_f32_16x16x32_f16(pa[0], wf[2][0], acc2, 0, 0, 0);
    acc2 = __builtin_amdgcn_mfma_f32_16x16x32_f16(pa[1], wf[2][1], acc2, 0, 0, 0);
    acc3 = __builtin_amdgcn_mfma_f32_16x16x32_f16(pa[0], wf[3][0], acc3, 0, 0, 0);
    acc3 = __builtin_amdgcn_mfma_f32_16x16x32_f16(pa[1], wf[3][1], acc3, 0, 0, 0);

    // ---- store: D layout col = lane&15, row = (lane>>4)*4 + reg ----
    #pragma unroll
    for (int r = 0; r < 4; ++r) {
        const int trow = (t0 + hi * 4 + r) * DIM;
        out[trow +  0 + t16] = acc0[r] + bj[0];
        out[trow + 16 + t16] = acc1[r] + bj[1];
        out[trow + 32 + t16] = acc2[r] + bj[2];
        out[trow + 48 + t16] = acc3[r] + bj[3];
    }
}

extern "C" void kernel_launch(void* const* d_in, const int* in_sizes, int n_in,
                              void* d_out, int out_size, void* d_ws, size_t ws_size,
                              hipStream_t stream) {
    const float* s   = (const float*)d_in[0];
    // d_in[1] is x — unused by the forward pass
    const float* A   = (const float*)d_in[2];
    const float* phi = (const float*)d_in[3];
    const float* w   = (const float*)d_in[4];
    const float* Wm  = (const float*)d_in[5];
    const float* b   = (const float*)d_in[6];
    float* out = (float*)d_out;

    dim3 grid(S_PTS / (4 * TPW));  // 512 blocks x 4 waves x 16 t = 32768
    dim3 block(256);
    hipLaunchKernelGGL(fourier_fused, grid, block, 0, stream,
                       s, A, phi, w, Wm, b, out);
}

// Round 11
// 19.033 us; speedup vs baseline: 1.0055x; 1.0055x over previous
//
#include <hip/hip_runtime.h>

// CoupledFourierSystem: out[t][j] = b[j] + sum_d W[j][d] * sum_{h,c} A[d][h][c]*cos(w[d][h][c]*s_t + phi[d][h][c])
// S=32768, DIM=64, H=16 (HC=32)
//
// Round 11: round-6 structure (pure v_cos phase A, swizzled LDS slab, f16 MFMA
// matvec) + harmonic-split wave pairs for 2x occupancy (diagnosed: latency-bound
// at 2 waves/SIMD, grid-limited).
//   - 1024 blocks x 4 waves; pair = wid>>1 owns 16 t; half = wid&1 computes
//     harmonics [half*16, half*16+16) -> partial slab pf[pair][half].
//   - After barrier: each wave sums both halves' A-fragments in-register and
//     computes output columns [half*32, half*32+32) with 4 MFMAs.

typedef float    f32x2 __attribute__((ext_vector_type(2)));
typedef float    f32x4 __attribute__((ext_vector_type(4)));
typedef _Float16 f16x8 __attribute__((ext_vector_type(8)));

constexpr int S_PTS = 32768;
constexpr int DIM   = 64;
constexpr int HC    = 32;   // H*2
constexpr int TPP   = 16;   // time points per wave-pair (MFMA M)
constexpr float INV_2PI = 0.15915494309189535f;

static __device__ __forceinline__ unsigned pkrtz(float x, float y) {
    return __builtin_bit_cast(unsigned, __builtin_amdgcn_cvt_pkrtz(x, y));
}
static __device__ __forceinline__ f16x8 pack8(f32x4 a, f32x4 b) {
    union { unsigned u[4]; f16x8 v; } t;
    t.u[0] = pkrtz(a[0], a[1]);
    t.u[1] = pkrtz(a[2], a[3]);
    t.u[2] = pkrtz(b[0], b[1]);
    t.u[3] = pkrtz(b[2], b[3]);
    return t.v;
}

__global__ __launch_bounds__(256, 4)
void fourier_fused(const float* __restrict__ s,
                   const float* __restrict__ A,
                   const float* __restrict__ phi,
                   const float* __restrict__ w,
                   const float* __restrict__ Wm,
                   const float* __restrict__ b,
                   float* __restrict__ out)
{
    __shared__ float pf[2][2][TPP * DIM];   // [pair][half] partial slabs, 32 KB

    const int lane = threadIdx.x & 63;
    const int wid  = threadIdx.x >> 6;
    const int pair = wid >> 1;
    const int half = wid & 1;
    const int t0   = blockIdx.x * (2 * TPP) + pair * TPP;
    const int t16  = lane & 15;
    const int hi   = lane >> 4;

    // ---- params: this half's 16 harmonics for d = lane, in revolutions ----
    f32x2 a2[8], w2[8], p2[8];
    {
        const float4* A4 = reinterpret_cast<const float4*>(A   + lane * HC + half * 16);
        const float4* P4 = reinterpret_cast<const float4*>(phi + lane * HC + half * 16);
        const float4* W4 = reinterpret_cast<const float4*>(w   + lane * HC + half * 16);
        #pragma unroll
        for (int q = 0; q < 4; ++q) {
            float4 av = A4[q], pv = P4[q], wv = W4[q];
            a2[2*q+0] = f32x2{av.x, av.y};           a2[2*q+1] = f32x2{av.z, av.w};
            p2[2*q+0] = f32x2{pv.x, pv.y} * INV_2PI; p2[2*q+1] = f32x2{pv.z, pv.w} * INV_2PI;
            w2[2*q+0] = f32x2{wv.x, wv.y} * INV_2PI; w2[2*q+1] = f32x2{wv.z, wv.w} * INV_2PI;
        }
    }

    // ---- B-fragments for this wave's 2 output n-blocks (cols half*32..+31) ----
    // B layout (16x16x32): col = lane&15, k = (lane>>4)*8 + j
    f16x8 wf[2][2];
    float bj[2];
    #pragma unroll
    for (int nn = 0; nn < 2; ++nn) {
        const int n = half * 2 + nn;
        const float* wr = Wm + (n * 16 + t16) * DIM;
        #pragma unroll
        for (int ks = 0; ks < 2; ++ks) {
            f32x4 v0 = *reinterpret_cast<const f32x4*>(wr + ks * 32 + hi * 8);
            f32x4 v1 = *reinterpret_cast<const f32x4*>(wr + ks * 32 + hi * 8 + 4);
            wf[nn][ks] = pack8(v0, v1);
        }
        bj[nn] = b[n * 16 + t16];
    }

    // lanes 0..15 hold the pair's 16 time values
    const float sv = s[t0 + t16];
    float* myslab = pf[pair][half];

    // ---- phase A: 16 partial Fourier sums -> swizzled slab ----
    #pragma unroll
    for (int k = 0; k < TPP; ++k) {
        const float st = __uint_as_float(__builtin_amdgcn_readlane(__float_as_uint(sv), k));
        const f32x2 st2 = {st, st};
        f32x2 ac0 = {0.f, 0.f}, ac1 = {0.f, 0.f};
        #pragma unroll
        for (int i = 0; i < 8; i += 2) {
            f32x2 ph0 = w2[i+0] * st2 + p2[i+0];   // v_pk_fma_f32
            f32x2 ph1 = w2[i+1] * st2 + p2[i+1];
            f32x2 c0 = { __builtin_amdgcn_cosf(ph0[0]), __builtin_amdgcn_cosf(ph0[1]) };
            f32x2 c1 = { __builtin_amdgcn_cosf(ph1[0]), __builtin_amdgcn_cosf(ph1[1]) };
            ac0 = a2[i+0] * c0 + ac0;
            ac1 = a2[i+1] * c1 + ac1;
        }
        const f32x2 acs = ac0 + ac1;
        myslab[(k * 64 + lane) ^ ((k & 7) << 2)] = acs[0] + acs[1];
    }
    __syncthreads();

    // ---- A-fragments: sum the pair's two partial slabs in-register ----
    // A layout (16x16x32): row = lane&15, k = (lane>>4)*8 + j
    const float* s0 = pf[pair][0];
    const float* s1 = pf[pair][1];
    f16x8 pa[2];
    #pragma unroll
    for (int ks = 0; ks < 2; ++ks) {
        const int base = t16 * 64 + ks * 32 + hi * 8;
        const int w0 = base       ^ ((t16 & 7) << 2);
        const int w1 = (base + 4) ^ ((t16 & 7) << 2);
        f32x4 q0 = *reinterpret_cast<const f32x4*>(s0 + w0)
                 + *reinterpret_cast<const f32x4*>(s1 + w0);
        f32x4 q1 = *reinterpret_cast<const f32x4*>(s0 + w1)
                 + *reinterpret_cast<const f32x4*>(s1 + w1);
        pa[ks] = pack8(q0, q1);
    }

    // ---- 4 MFMAs: this wave's half of the output columns ----
    f32x4 acc0 = {}, acc1 = {};
    acc0 = __builtin_amdgcn_mfma_f32_16x16x32_f16(pa[0], wf[0][0], acc0, 0, 0, 0);
    acc0 = __builtin_amdgcn_mfma_f32_16x16x32_f16(pa[1], wf[0][1], acc0, 0, 0, 0);
    acc1 = __builtin_amdgcn_mfma_f32_16x16x32_f16(pa[0], wf[1][0], acc1, 0, 0, 0);
    acc1 = __builtin_amdgcn_mfma_f32_16x16x32_f16(pa[1], wf[1][1], acc1, 0, 0, 0);

    // ---- store: D layout col = lane&15, row = (lane>>4)*4 + reg ----
    const int c0 = half * 32 + t16;
    #pragma unroll
    for (int r = 0; r < 4; ++r) {
        const int trow = (t0 + hi * 4 + r) * DIM;
        out[trow + c0 +  0] = acc0[r] + bj[0];
        out[trow + c0 + 16] = acc1[r] + bj[1];
    }
}

extern "C" void kernel_launch(void* const* d_in, const int* in_sizes, int n_in,
                              void* d_out, int out_size, void* d_ws, size_t ws_size,
                              hipStream_t stream) {
    const float* s   = (const float*)d_in[0];
    // d_in[1] is x — unused by the forward pass
    const float* A   = (const float*)d_in[2];
    const float* phi = (const float*)d_in[3];
    const float* w   = (const float*)d_in[4];
    const float* Wm  = (const float*)d_in[5];
    const float* b   = (const float*)d_in[6];
    float* out = (float*)d_out;

    dim3 grid(S_PTS / (2 * TPP));   // 1024 blocks x (2 pairs x 16 t) = 32768
    dim3 block(256);
    hipLaunchKernelGGL(fourier_fused, grid, block, 0, stream,
                       s, A, phi, w, Wm, b, out);
}